// Round 6
// baseline (194.180 us; speedup 1.0000x reference)
//
#include <hip/hip_runtime.h>

// QuantizedActorMLP: x(1M,17) -> quant -> L1(17->64)+quantact -> L2(64->64)+quantact -> L3(64->6)
// Integer-exact bf16 MFMA (ints |n|<=127 exact in bf16, sums < 2^24 exact in fp32 acc).
// R15: TWO-PHASE split. Evidence: R10/R11/R13 (three different staging mechanisms) all sit
//      at ~1.9-2.0 TB/s effective while pure streams measure 4.9-6.3 TB/s and R14's spill
//      traffic proved >=2.4 TB/s delivery. Theory: the interleaved load+MFMA+store loop
//      structure is the cap, not bytes/requests/occupancy. So:
//   K1 qquant: pure copy-shaped stream, x f32 -> packed bf16 int codes Xq in d_ws
//              (dense grid-stride float4 -> uint2 stores; same qclamp/pack2 math).
//   K2 qmlp2:  per 16-row tile, B-frag = ONE dwordx4/lane from Xq (zero conversion VALU,
//              no LDS input path, no global_load_lds, no manual vmcnt); Xq is L3-hot.
//              Weights preamble + MFMA core + funnel store verbatim; biases in LDS tables.
//   Fallback:  if ws_size < B*17*2 bytes, run the verified R13 single-kernel (included).

typedef __attribute__((ext_vector_type(8))) short short8;    // MFMA A/B frag (8 bf16)
typedef __attribute__((ext_vector_type(4))) float floatx4;   // MFMA C/D frag
typedef __attribute__((ext_vector_type(4))) unsigned int uint4v;
typedef __attribute__((ext_vector_type(2))) unsigned int uint2v;
typedef __attribute__((ext_vector_type(4), aligned(4))) unsigned int uint4u; // 4B-aligned 16B load
typedef unsigned int uint;

__device__ __forceinline__ uint f32bits(float v) { union { float f; uint u; } c; c.f = v; return c.u; }
__device__ __forceinline__ short bf16i(float v) { return (short)(f32bits(v) >> 16); }
// pack two integer-valued f32 -> two bf16 in one uint (low = z0): one v_perm_b32
__device__ __forceinline__ uint pack2(float z0, float z1) {
  return __builtin_amdgcn_perm(f32bits(z1), f32bits(z0), 0x07060302u);
}
// round-to-nearest-even integer clamped to [-127,127]: v_med3 + v_rndne
__device__ __forceinline__ float qclamp(float v) {
  return __builtin_rintf(__builtin_amdgcn_fmed3f(v, -127.f, 127.f));
}
__device__ __forceinline__ int imin(int a, int b) { return a < b ? a : b; }

// ============================ K1: streaming input quant ============================
__global__ void __launch_bounds__(256) qquant(
    const float* __restrict__ x, uint2v* __restrict__ xq8, int nquads)
{
  constexpr float QMAXF = 127.0f;
  constexpr float SCALE = 1.33f;
  const float istep = QMAXF / SCALE;
  int g      = blockIdx.x * blockDim.x + threadIdx.x;
  int stride = gridDim.x * blockDim.x;
  for (; g < nquads; g += stride) {
    float4 v = ((const float4*)x)[g];                          // dense 1KB/wave loads
    uint lo = pack2(qclamp(v.x * istep), qclamp(v.y * istep)); // bf16[e0,e1]
    uint hi = pack2(qclamp(v.z * istep), qclamp(v.w * istep)); // bf16[e2,e3]
    uint2v o; o.x = lo; o.y = hi;
    xq8[g] = o;                                                // dense 512B/wave stores
  }
}

// ============================ K2: MLP from packed Xq ============================
__global__ void __launch_bounds__(256) qmlp2(
    const unsigned short* __restrict__ xq,
    const float* __restrict__ W1, const float* __restrict__ b1,
    const float* __restrict__ W2, const float* __restrict__ b2,
    const float* __restrict__ W3, const float* __restrict__ b3,
    float* __restrict__ out, int B)
{
  constexpr float QMAXF = 127.0f;
  constexpr float SCALE = 1.33f;
  const float step  = SCALE / QMAXF;
  const float istep = QMAXF / SCALE;

  // preamble: wraw1[0..1088) wraw2[1088..5248) wraw3[5248..5638) redv[5638..5650)
  // persistent: bias tables [5650..5794);  main loop: out funnels overlay wraw1[0..416)
  __shared__ __align__(16) float smem[5794];
  float* wraw1 = smem;
  float* wraw2 = smem + 1088;
  float* wraw3 = smem + 5248;
  float* redv  = smem + 5638;
  float* b1t   = smem + 5650;     // b1[n]*istep
  float* b2t   = smem + 5714;     // b2[n]*istep
  float* b3t   = smem + 5778;     // b3[n] (n<6) else 0

  const int tid  = threadIdx.x;
  const int lane = tid & 63;
  const int bi   = lane & 15;
  const int q    = lane >> 4;
  const int w    = tid >> 6;

  // ---- coalesced staging of raw weights into LDS, max-abs fused into the load ----
  float m1 = 0.f, m2 = 0.f, m3 = 0.f;
  for (int i = tid; i < 272; i += 256) {
    float4 v = ((const float4*)W1)[i];
    ((float4*)wraw1)[i] = v;
    m1 = fmaxf(m1, fmaxf(fmaxf(fabsf(v.x), fabsf(v.y)), fmaxf(fabsf(v.z), fabsf(v.w))));
  }
  for (int i = tid; i < 1024; i += 256) {
    float4 v = ((const float4*)W2)[i];
    int r = i >> 4, c0 = (i & 15) * 4;
    float* dst = &wraw2[r * 65 + c0];
    dst[0] = v.x; dst[1] = v.y; dst[2] = v.z; dst[3] = v.w;
    m2 = fmaxf(m2, fmaxf(fmaxf(fabsf(v.x), fabsf(v.y)), fmaxf(fabsf(v.z), fabsf(v.w))));
  }
  for (int i = tid; i < 96; i += 256) {
    float4 v = ((const float4*)W3)[i];
    int r = i >> 4, c0 = (i & 15) * 4;
    float* dst = &wraw3[r * 65 + c0];
    dst[0] = v.x; dst[1] = v.y; dst[2] = v.z; dst[3] = v.w;
    m3 = fmaxf(m3, fmaxf(fmaxf(fabsf(v.x), fabsf(v.y)), fmaxf(fabsf(v.z), fabsf(v.w))));
  }
  if (tid < 64) {
    b1t[tid] = b1[tid] * istep;
    b2t[tid] = b2[tid] * istep;
  }
  if (tid < 16) b3t[tid] = (tid < 6) ? b3[tid] : 0.f;

  #pragma unroll
  for (int off = 32; off > 0; off >>= 1) {
    m1 = fmaxf(m1, __shfl_down(m1, off));
    m2 = fmaxf(m2, __shfl_down(m2, off));
    m3 = fmaxf(m3, __shfl_down(m3, off));
  }
  if (lane == 0) {
    redv[w * 3 + 0] = m1; redv[w * 3 + 1] = m2; redv[w * 3 + 2] = m3;
  }
  __syncthreads();                 // barrier 1: publishes redv + wraw1/2/3 + bias tables
  float s1 = 0.f, s2 = 0.f, s3 = 0.f;
  #pragma unroll
  for (int i = 0; i < 4; ++i) {
    s1 = fmaxf(s1, redv[i * 3 + 0]);
    s2 = fmaxf(s2, redv[i * 3 + 1]);
    s3 = fmaxf(s3, redv[i * 3 + 2]);
  }
  s1 /= QMAXF; s2 /= QMAXF; s3 /= QMAXF;
  const float rs1 = 1.0f / s1, rs2 = 1.0f / s2, rs3 = 1.0f / s3;

  // ---- weight fragments (integer-valued bf16) from LDS ----
  short8 w1f[4];
  #pragma unroll
  for (int t = 0; t < 4; ++t) {
    #pragma unroll
    for (int j = 0; j < 8; ++j) {
      int k = 8 * q + j;
      float wv = (k < 17) ? wraw1[(16 * t + bi) * 17 + k] : 0.f;
      float wi = fminf(fmaxf(rintf(wv * rs1), -QMAXF), QMAXF);
      w1f[t][j] = bf16i(wi);
    }
  }
  // K-permutation: eta = 32s + 16(j>>2) + 4q + (j&3)
  short8 w2f[4][2];
  #pragma unroll
  for (int t = 0; t < 4; ++t) {
    #pragma unroll
    for (int s = 0; s < 2; ++s) {
      #pragma unroll
      for (int j = 0; j < 8; ++j) {
        int eta = 32 * s + 16 * (j >> 2) + 4 * q + (j & 3);
        float wv = wraw2[(16 * t + bi) * 65 + eta];
        float wi = fminf(fmaxf(rintf(wv * rs2), -QMAXF), QMAXF);
        w2f[t][s][j] = bf16i(wi);
      }
    }
  }
  short8 w3f[2];
  #pragma unroll
  for (int s = 0; s < 2; ++s) {
    #pragma unroll
    for (int j = 0; j < 8; ++j) {
      int eta = 32 * s + 16 * (j >> 2) + 4 * q + (j & 3);
      float wv = (bi < 6) ? wraw3[bi * 65 + eta] : 0.f;
      float wi = fminf(fmaxf(rintf(wv * rs3), -QMAXF), QMAXF);
      w3f[s][j] = bf16i(wi);
    }
  }

  __syncthreads();                 // barrier 2: wraw1 dead -> funnel overlay is safe

  const float g1 = (s1 * step) * istep;
  const float g2 = (s2 * step) * istep;
  const float sc3 = s3 * step;

  const int ntiles = B >> 4;                                   // 65536
  const int nw     = (int)(gridDim.x << 2);                    // 4096 waves
  const int wid    = __builtin_amdgcn_readfirstlane((int)(blockIdx.x << 2) + w);
  const int TPW    = (ntiles + nw - 1) / nw;                   // 16 consecutive tiles/wave
  const int lastt  = ntiles - 1;

  float* obuf = smem + w * 104;                                // out funnel (overlay wraw1)

  const char* xqb = (const char*)xq;
  const int lo4  = bi * 34 + ((q < 2) ? 16 * q : 0);           // dwordx4 offset (dummy for q>=2)
  const int lo2  = bi * 34 + 32;                               // elem16 ushort offset
  const int lane4 = lane * 4;

  const floatx4 zero4 = {0.f, 0.f, 0.f, 0.f};

  struct PF { uint4u v; uint u; };
  auto loadpf = [&](int t, PF& p) {
    const char* rp = xqb + (size_t)t * 544;
    p.v = *(const uint4u*)(rp + lo4);                          // one 16B load/lane (L3-hot)
    p.u = *(const unsigned short*)(rp + lo2);
  };
  auto mkfrag = [&](const PF& p) -> short8 {
    uint4v ap;
    ap[0] = (q == 3) ? 0u : ((q == 2) ? p.u : p.v.x);
    ap[1] = (q >= 2) ? 0u : p.v.y;
    ap[2] = (q >= 2) ? 0u : p.v.z;
    ap[3] = (q >= 2) ? 0u : p.v.w;
    return __builtin_bit_cast(short8, ap);
  };

  auto mlp_store = [&](short8 af, int gt) {
    // L1
    floatx4 c1[4];
    #pragma unroll
    for (int t = 0; t < 4; ++t)
      c1[t] = __builtin_amdgcn_mfma_f32_16x16x32_bf16(w1f[t], af, zero4, 0, 0, 0);

    uint4v h1u[2];
    #pragma unroll
    for (int t = 0; t < 4; ++t) {
      float4 bb = *(const float4*)(b1t + 16 * t + 4 * q);      // broadcast ds_read_b128
      float z0 = qclamp(fmaf(c1[t][0], g1, bb.x));
      float z1 = qclamp(fmaf(c1[t][1], g1, bb.y));
      float z2 = qclamp(fmaf(c1[t][2], g1, bb.z));
      float z3 = qclamp(fmaf(c1[t][3], g1, bb.w));
      h1u[t >> 1][(t & 1) * 2 + 0] = pack2(z0, z1);
      h1u[t >> 1][(t & 1) * 2 + 1] = pack2(z2, z3);
    }
    short8 h1a = __builtin_bit_cast(short8, h1u[0]);
    short8 h1b = __builtin_bit_cast(short8, h1u[1]);

    // L2 (K=64)
    floatx4 c2[4];
    #pragma unroll
    for (int t = 0; t < 4; ++t) {
      c2[t] = __builtin_amdgcn_mfma_f32_16x16x32_bf16(w2f[t][0], h1a, zero4, 0, 0, 0);
      c2[t] = __builtin_amdgcn_mfma_f32_16x16x32_bf16(w2f[t][1], h1b, c2[t], 0, 0, 0);
    }

    uint4v h2u[2];
    #pragma unroll
    for (int t = 0; t < 4; ++t) {
      float4 bb = *(const float4*)(b2t + 16 * t + 4 * q);
      float z0 = qclamp(fmaf(c2[t][0], g2, bb.x));
      float z1 = qclamp(fmaf(c2[t][1], g2, bb.y));
      float z2 = qclamp(fmaf(c2[t][2], g2, bb.z));
      float z3 = qclamp(fmaf(c2[t][3], g2, bb.w));
      h2u[t >> 1][(t & 1) * 2 + 0] = pack2(z0, z1);
      h2u[t >> 1][(t & 1) * 2 + 1] = pack2(z2, z3);
    }
    short8 h2a = __builtin_bit_cast(short8, h2u[0]);
    short8 h2b = __builtin_bit_cast(short8, h2u[1]);

    // L3
    floatx4 c3;
    c3 = __builtin_amdgcn_mfma_f32_16x16x32_bf16(w3f[0], h2a, zero4, 0, 0, 0);
    c3 = __builtin_amdgcn_mfma_f32_16x16x32_bf16(w3f[1], h2b, c3, 0, 0, 0);

    float4 b3v = *(const float4*)(b3t + 4 * q);
    float o0 = fmaf(c3[0], sc3, b3v.x);
    float o1 = fmaf(c3[1], sc3, b3v.y);
    float o2 = fmaf(c3[2], sc3, b3v.z);
    float o3 = fmaf(c3[3], sc3, b3v.w);

    // funnel 16x6 tile through LDS -> one coalesced dwordx4 store (lanes 0..23)
    if (q == 0) {
      *(float2*)(obuf + bi * 6)     = make_float2(o0, o1);     // ds_write_b64, 24B stride
      *(float2*)(obuf + bi * 6 + 2) = make_float2(o2, o3);
    } else if (q == 1) {
      *(float2*)(obuf + bi * 6 + 4) = make_float2(o0, o1);
    }
    asm volatile("" ::: "memory");                             // pin intra-wave LDS order
    if (lane < 24) {
      float4 v = *(const float4*)(obuf + lane4);               // ds_read_b128
      *(float4*)(out + (size_t)gt * 96 + lane4) = v;           // one dwordx4 (6 lines)
    }
  };

  // ---- main loop: 16 consecutive tiles/wave, depth-2 register prefetch ----
  const int t0 = wid * TPW;
  PF A, Bp;
  loadpf(imin(t0, lastt), A);
  loadpf(imin(t0 + 1, lastt), Bp);
  #pragma unroll 1
  for (int tt = 0; tt < TPW; tt += 2) {
    short8 af = mkfrag(A);
    if (tt + 2 < TPW) loadpf(imin(t0 + tt + 2, lastt), A);
    mlp_store(af, imin(t0 + tt, lastt));
    short8 bf = mkfrag(Bp);
    if (tt + 3 < TPW) loadpf(imin(t0 + tt + 3, lastt), Bp);
    mlp_store(bf, imin(t0 + tt + 1, lastt));
  }
}

// ============================ Fallback: verified R13 single kernel ============================
__device__ __forceinline__ void gld16(const float* g, float* l) {
  __builtin_amdgcn_global_load_lds((__attribute__((address_space(1))) void*)(g),
                                   (__attribute__((address_space(3))) void*)(l),
                                   16, 0, 0);
}
__device__ __forceinline__ void gld4(const float* g, float* l) {
  __builtin_amdgcn_global_load_lds((__attribute__((address_space(1))) void*)(g),
                                   (__attribute__((address_space(3))) void*)(l),
                                   4, 0, 0);
}

__global__ void __launch_bounds__(256) qmlp_fused(
    const float* __restrict__ x,
    const float* __restrict__ W1, const float* __restrict__ b1,
    const float* __restrict__ W2, const float* __restrict__ b2,
    const float* __restrict__ W3, const float* __restrict__ b3,
    float* __restrict__ out, int B)
{
  constexpr float QMAXF = 127.0f;
  constexpr float SCALE = 1.33f;
  const float step  = SCALE / QMAXF;
  const float istep = QMAXF / SCALE;

  __shared__ __align__(16) float smem[8704];
  float* wraw1 = smem;
  float* wraw2 = smem + 1088;
  float* wraw3 = smem + 5248;
  float* redv  = smem + 5638;

  const int tid  = threadIdx.x;
  const int lane = tid & 63;
  const int bi   = lane & 15;
  const int q    = lane >> 4;
  const int w    = tid >> 6;

  float m1 = 0.f, m2 = 0.f, m3 = 0.f;
  for (int i = tid; i < 272; i += 256) {
    float4 v = ((const float4*)W1)[i];
    ((float4*)wraw1)[i] = v;
    m1 = fmaxf(m1, fmaxf(fmaxf(fabsf(v.x), fabsf(v.y)), fmaxf(fabsf(v.z), fabsf(v.w))));
  }
  for (int i = tid; i < 1024; i += 256) {
    float4 v = ((const float4*)W2)[i];
    int r = i >> 4, c0 = (i & 15) * 4;
    float* dst = &wraw2[r * 65 + c0];
    dst[0] = v.x; dst[1] = v.y; dst[2] = v.z; dst[3] = v.w;
    m2 = fmaxf(m2, fmaxf(fmaxf(fabsf(v.x), fabsf(v.y)), fmaxf(fabsf(v.z), fabsf(v.w))));
  }
  for (int i = tid; i < 96; i += 256) {
    float4 v = ((const float4*)W3)[i];
    int r = i >> 4, c0 = (i & 15) * 4;
    float* dst = &wraw3[r * 65 + c0];
    dst[0] = v.x; dst[1] = v.y; dst[2] = v.z; dst[3] = v.w;
    m3 = fmaxf(m3, fmaxf(fmaxf(fabsf(v.x), fabsf(v.y)), fmaxf(fabsf(v.z), fabsf(v.w))));
  }
  #pragma unroll
  for (int off = 32; off > 0; off >>= 1) {
    m1 = fmaxf(m1, __shfl_down(m1, off));
    m2 = fmaxf(m2, __shfl_down(m2, off));
    m3 = fmaxf(m3, __shfl_down(m3, off));
  }
  if (lane == 0) {
    redv[w * 3 + 0] = m1; redv[w * 3 + 1] = m2; redv[w * 3 + 2] = m3;
  }
  __syncthreads();
  float s1 = 0.f, s2 = 0.f, s3 = 0.f;
  #pragma unroll
  for (int i = 0; i < 4; ++i) {
    s1 = fmaxf(s1, redv[i * 3 + 0]);
    s2 = fmaxf(s2, redv[i * 3 + 1]);
    s3 = fmaxf(s3, redv[i * 3 + 2]);
  }
  s1 /= QMAXF; s2 /= QMAXF; s3 /= QMAXF;
  const float rs1 = 1.0f / s1, rs2 = 1.0f / s2, rs3 = 1.0f / s3;

  short8 w1f[4];
  #pragma unroll
  for (int t = 0; t < 4; ++t) {
    #pragma unroll
    for (int j = 0; j < 8; ++j) {
      int k = 8 * q + j;
      float wv = (k < 17) ? wraw1[(16 * t + bi) * 17 + k] : 0.f;
      float wi = fminf(fmaxf(rintf(wv * rs1), -QMAXF), QMAXF);
      w1f[t][j] = bf16i(wi);
    }
  }
  short8 w2f[4][2];
  #pragma unroll
  for (int t = 0; t < 4; ++t) {
    #pragma unroll
    for (int s = 0; s < 2; ++s) {
      #pragma unroll
      for (int j = 0; j < 8; ++j) {
        int eta = 32 * s + 16 * (j >> 2) + 4 * q + (j & 3);
        float wv = wraw2[(16 * t + bi) * 65 + eta];
        float wi = fminf(fmaxf(rintf(wv * rs2), -QMAXF), QMAXF);
        w2f[t][s][j] = bf16i(wi);
      }
    }
  }
  short8 w3f[2];
  #pragma unroll
  for (int s = 0; s < 2; ++s) {
    #pragma unroll
    for (int j = 0; j < 8; ++j) {
      int eta = 32 * s + 16 * (j >> 2) + 4 * q + (j & 3);
      float wv = (bi < 6) ? wraw3[bi * 65 + eta] : 0.f;
      float wi = fminf(fmaxf(rintf(wv * rs3), -QMAXF), QMAXF);
      w3f[s][j] = bf16i(wi);
    }
  }

  __syncthreads();

  const float g1 = (s1 * step) * istep;
  const float g2 = (s2 * step) * istep;
  const float sc3 = s3 * step;
  float b1s[4][4], b2s[4][4], b3s[4];
  #pragma unroll
  for (int t = 0; t < 4; ++t) {
    #pragma unroll
    for (int r = 0; r < 4; ++r) {
      b1s[t][r] = b1[16 * t + 4 * q + r] * istep;
      b2s[t][r] = b2[16 * t + 4 * q + r] * istep;
    }
  }
  #pragma unroll
  for (int r = 0; r < 4; ++r) {
    int n = 4 * q + r;
    b3s[r] = (n < 6) ? b3[n] : 0.f;
  }

  const int ntiles = B >> 4;
  const int nSup   = ntiles >> 2;
  const int nw     = (int)(gridDim.x << 2);
  const int wid    = __builtin_amdgcn_readfirstlane((int)(blockIdx.x << 2) + w);
  const int nIter  = (nSup + nw - 1) / nw;
  const int lastS  = nSup - 1;

  float* xb = smem + w * 2176;
  const int lane4 = lane * 4;
  const int fbase = bi * 17 + 8 * q;
  const int fb2   = bi * 17 + 16;

  auto stage = [&](int s, float* buf) {
    const float* tp = x + (size_t)s * 1088;
    gld16(tp + lane4,        buf);
    gld16(tp + 256 + lane4,  buf + 256);
    gld16(tp + 512 + lane4,  buf + 512);
    gld16(tp + 768 + lane4,  buf + 768);
    gld4 (tp + 1024 + lane,  buf + 1024);
  };

  const floatx4 zero4 = {0.f, 0.f, 0.f, 0.f};
  stage(imin(wid, lastS), xb);

  #pragma unroll 1
  for (int it = 0; it < nIter; ++it) {
    const int gs = imin(wid + it * nw, lastS);
    float* cur = xb + (it & 1) * 1088;

    if (it == 0) { asm volatile("s_waitcnt vmcnt(0)" ::: "memory"); }
    else         { asm volatile("s_waitcnt vmcnt(2)" ::: "memory"); }

    if (it + 1 < nIter) stage(imin(wid + (it + 1) * nw, lastS), xb + ((it + 1) & 1) * 1088);

    #pragma unroll 1
    for (int k = 0; k < 4; ++k) {
      float* tb = cur + k * 272;
      float xr[8];
      if (q < 2) {
        #pragma unroll
        for (int j = 0; j < 8; ++j) xr[j] = tb[fbase + j];
      } else if (q == 2) {
        xr[0] = tb[fb2];
        #pragma unroll
        for (int j = 1; j < 8; ++j) xr[j] = 0.f;
      } else {
        #pragma unroll
        for (int j = 0; j < 8; ++j) xr[j] = 0.f;
      }

      uint4v ap;
      #pragma unroll
      for (int jp = 0; jp < 4; ++jp)
        ap[jp] = pack2(qclamp(xr[2 * jp] * istep), qclamp(xr[2 * jp + 1] * istep));
      short8 af = __builtin_bit_cast(short8, ap);

      floatx4 c1[4];
      #pragma unroll
      for (int t = 0; t < 4; ++t)
        c1[t] = __builtin_amdgcn_mfma_f32_16x16x32_bf16(w1f[t], af, zero4, 0, 0, 0);

      uint4v h1u[2];
      #pragma unroll
      for (int t = 0; t < 4; ++t) {
        float z0 = qclamp(fmaf(c1[t][0], g1, b1s[t][0]));
        float z1 = qclamp(fmaf(c1[t][1], g1, b1s[t][1]));
        float z2 = qclamp(fmaf(c1[t][2], g1, b1s[t][2]));
        float z3 = qclamp(fmaf(c1[t][3], g1, b1s[t][3]));
        h1u[t >> 1][(t & 1) * 2 + 0] = pack2(z0, z1);
        h1u[t >> 1][(t & 1) * 2 + 1] = pack2(z2, z3);
      }
      short8 h1a = __builtin_bit_cast(short8, h1u[0]);
      short8 h1b = __builtin_bit_cast(short8, h1u[1]);

      floatx4 c2[4];
      #pragma unroll
      for (int t = 0; t < 4; ++t) {
        c2[t] = __builtin_amdgcn_mfma_f32_16x16x32_bf16(w2f[t][0], h1a, zero4, 0, 0, 0);
        c2[t] = __builtin_amdgcn_mfma_f32_16x16x32_bf16(w2f[t][1], h1b, c2[t], 0, 0, 0);
      }

      uint4v h2u[2];
      #pragma unroll
      for (int t = 0; t < 4; ++t) {
        float z0 = qclamp(fmaf(c2[t][0], g2, b2s[t][0]));
        float z1 = qclamp(fmaf(c2[t][1], g2, b2s[t][1]));
        float z2 = qclamp(fmaf(c2[t][2], g2, b2s[t][2]));
        float z3 = qclamp(fmaf(c2[t][3], g2, b2s[t][3]));
        h2u[t >> 1][(t & 1) * 2 + 0] = pack2(z0, z1);
        h2u[t >> 1][(t & 1) * 2 + 1] = pack2(z2, z3);
      }
      short8 h2a = __builtin_bit_cast(short8, h2u[0]);
      short8 h2b = __builtin_bit_cast(short8, h2u[1]);

      floatx4 c3;
      c3 = __builtin_amdgcn_mfma_f32_16x16x32_bf16(w3f[0], h2a, zero4, 0, 0, 0);
      c3 = __builtin_amdgcn_mfma_f32_16x16x32_bf16(w3f[1], h2b, c3, 0, 0, 0);

      float o0 = fmaf(c3[0], sc3, b3s[0]);
      float o1 = fmaf(c3[1], sc3, b3s[1]);
      float o2 = fmaf(c3[2], sc3, b3s[2]);
      float o3 = fmaf(c3[3], sc3, b3s[3]);

      float* ob = cur + k * 96;
      if (q == 0) {
        *(float2*)(ob + bi * 6)     = make_float2(o0, o1);
        *(float2*)(ob + bi * 6 + 2) = make_float2(o2, o3);
      } else if (q == 1) {
        *(float2*)(ob + bi * 6 + 4) = make_float2(o0, o1);
      }
    }

    asm volatile("" ::: "memory");
    {
      float4 v0 = *(const float4*)(cur + lane4);
      *(float4*)(out + (size_t)gs * 384 + lane4) = v0;
      if (lane < 32) {
        float4 v1 = *(const float4*)(cur + 256 + lane4);
        *(float4*)(out + (size_t)gs * 384 + 256 + lane4) = v1;
      }
    }
  }
}

extern "C" void kernel_launch(void* const* d_in, const int* in_sizes, int n_in,
                              void* d_out, int out_size, void* d_ws, size_t ws_size,
                              hipStream_t stream) {
  const float* x  = (const float*)d_in[0];
  const float* W1 = (const float*)d_in[1];
  const float* b1 = (const float*)d_in[2];
  const float* W2 = (const float*)d_in[3];
  const float* b2 = (const float*)d_in[4];
  const float* W3 = (const float*)d_in[5];
  const float* b3 = (const float*)d_in[6];
  float* out = (float*)d_out;
  const int B = in_sizes[0] / 17;          // 1048576

  const size_t xq_bytes = (size_t)B * 17 * 2;   // packed bf16 codes, 34 MB
  if (d_ws != nullptr && ws_size >= xq_bytes) {
    const int nquads = (B * 17) / 4;            // 4,456,448 float4s
    qquant<<<dim3(2048), dim3(256), 0, stream>>>(x, (uint2v*)d_ws, nquads);
    qmlp2<<<dim3(1024), dim3(256), 0, stream>>>((const unsigned short*)d_ws,
                                                W1, b1, W2, b2, W3, b3, out, B);
  } else {
    qmlp_fused<<<dim3(1024), dim3(256), 0, stream>>>(x, W1, b1, W2, b2, W3, b3, out, B);
  }
}

// Round 7
// 189.845 us; speedup vs baseline: 1.0228x; 1.0228x over previous
//
#include <hip/hip_runtime.h>

// QuantizedActorMLP: x(1M,17) -> quant -> L1(17->64)+quantact -> L2(64->64)+quantact -> L3(64->6)
// Integer-exact bf16 MFMA (ints |n|<=127 exact in bf16, sums < 2^24 exact in fp32 acc).
// R16: occupancy push WITHOUT a register cap. Evidence chain:
//  - R13 (51us): VALUBusy 50% == hand-counted VALU at 4 waves/SIMD; other 50% = unhidden
//    memory latency. VALU floor ~7.5us, memory floor ~15us -> need more resident waves.
//  - R14 failed ONLY because launch_bounds(256,5) capped VGPR at 102 < need(~110 with
//    36 bias VGPRs) -> allocator spilled the persistent weight frags (WRITE_SIZE 5x).
//  - R15 qmlp2 proved: same MFMA core + biases in LDS tables = 84 VGPR naturally.
//  => R16 = R13's verified staging/compute/funnel + bias LDS tables + 2-tile supertiles
//     (LDS/block 23.2KB), DEFAULT launch bounds. Occupancy = floor(512/VGPR) ~ 5-6
//     waves/SIMD, LDS allows 7 blocks/CU. Grid 1280, scalar-guarded 6-7 supertiles/wave.
//  Falsifier: if VGPR>102 or WRITE_SIZE jumps -> allocator misbehaved, revert to R13.

typedef __attribute__((ext_vector_type(8))) short short8;    // MFMA A/B frag (8 bf16)
typedef __attribute__((ext_vector_type(4))) float floatx4;   // MFMA C/D frag
typedef __attribute__((ext_vector_type(4))) unsigned int uint4v;
typedef unsigned int uint;

__device__ __forceinline__ uint f32bits(float v) { union { float f; uint u; } c; c.f = v; return c.u; }
__device__ __forceinline__ short bf16i(float v) { return (short)(f32bits(v) >> 16); }
// pack two integer-valued f32 -> two bf16 in one uint (low = z0): one v_perm_b32
__device__ __forceinline__ uint pack2(float z0, float z1) {
  return __builtin_amdgcn_perm(f32bits(z1), f32bits(z0), 0x07060302u);
}
// round-to-nearest-even integer clamped to [-127,127]: v_med3 + v_rndne
__device__ __forceinline__ float qclamp(float v) {
  return __builtin_rintf(__builtin_amdgcn_fmed3f(v, -127.f, 127.f));
}
__device__ __forceinline__ int imin(int a, int b) { return a < b ? a : b; }

// async global->LDS: LDS dest = (uniform) l + lane*size, global src per-lane.
__device__ __forceinline__ void gld16(const float* g, float* l) {
  __builtin_amdgcn_global_load_lds((__attribute__((address_space(1))) void*)(g),
                                   (__attribute__((address_space(3))) void*)(l),
                                   16, 0, 0);
}
__device__ __forceinline__ void gld4(const float* g, float* l) {
  __builtin_amdgcn_global_load_lds((__attribute__((address_space(1))) void*)(g),
                                   (__attribute__((address_space(3))) void*)(l),
                                   4, 0, 0);
}

__global__ void __launch_bounds__(256) qmlp_fused(
    const float* __restrict__ x,
    const float* __restrict__ W1, const float* __restrict__ b1,
    const float* __restrict__ W2, const float* __restrict__ b2,
    const float* __restrict__ W3, const float* __restrict__ b3,
    float* __restrict__ out, int B)
{
  constexpr float QMAXF = 127.0f;
  constexpr float SCALE = 1.33f;
  const float step  = SCALE / QMAXF;
  const float istep = QMAXF / SCALE;

  // One shared pool, two lifetimes:
  //  preamble: wraw1[0..1088) wraw2[1088..5248) wraw3[5248..5638) redv[5638..5650)
  //  main loop: per-wave x double-buffer [w*1152 + d*576, +576)   (4608 dw, overlays wraw*)
  //  persistent: bias tables b1t[5650..5714) b2t[5714..5778) b3t[5778..5794)
  __shared__ __align__(16) float smem[5794];
  float* wraw1 = smem;            // W1 raw, pitch 17
  float* wraw2 = smem + 1088;     // W2 raw, pitch 65 (pad kills gather conflicts)
  float* wraw3 = smem + 5248;     // W3 raw, pitch 65
  float* redv  = smem + 5638;     // per-wave (m1,m2,m3)
  float* b1t   = smem + 5650;     // b1[n]*istep
  float* b2t   = smem + 5714;     // b2[n]*istep
  float* b3t   = smem + 5778;     // b3[n] (n<6) else 0

  const int tid  = threadIdx.x;
  const int lane = tid & 63;
  const int bi   = lane & 15;
  const int q    = lane >> 4;
  const int w    = tid >> 6;

  // ---- coalesced staging of raw weights into LDS, max-abs fused into the load ----
  float m1 = 0.f, m2 = 0.f, m3 = 0.f;
  for (int i = tid; i < 272; i += 256) {                       // W1: 1088 floats = 272 float4
    float4 v = ((const float4*)W1)[i];
    ((float4*)wraw1)[i] = v;
    m1 = fmaxf(m1, fmaxf(fmaxf(fabsf(v.x), fabsf(v.y)), fmaxf(fabsf(v.z), fabsf(v.w))));
  }
  for (int i = tid; i < 1024; i += 256) {                      // W2: 4096 floats = 1024 float4
    float4 v = ((const float4*)W2)[i];
    int r = i >> 4, c0 = (i & 15) * 4;                         // no float4 crosses a 64-row
    float* dst = &wraw2[r * 65 + c0];
    dst[0] = v.x; dst[1] = v.y; dst[2] = v.z; dst[3] = v.w;
    m2 = fmaxf(m2, fmaxf(fmaxf(fabsf(v.x), fabsf(v.y)), fmaxf(fabsf(v.z), fabsf(v.w))));
  }
  for (int i = tid; i < 96; i += 256) {                        // W3: 384 floats = 96 float4
    float4 v = ((const float4*)W3)[i];
    int r = i >> 4, c0 = (i & 15) * 4;
    float* dst = &wraw3[r * 65 + c0];
    dst[0] = v.x; dst[1] = v.y; dst[2] = v.z; dst[3] = v.w;
    m3 = fmaxf(m3, fmaxf(fmaxf(fabsf(v.x), fabsf(v.y)), fmaxf(fabsf(v.z), fabsf(v.w))));
  }
  // bias tables (persistent region, disjoint from wraw* and x-buffers): written once
  if (tid < 64) {
    b1t[tid] = b1[tid] * istep;
    b2t[tid] = b2[tid] * istep;
  }
  if (tid < 16) b3t[tid] = (tid < 6) ? b3[tid] : 0.f;

  #pragma unroll
  for (int off = 32; off > 0; off >>= 1) {
    m1 = fmaxf(m1, __shfl_down(m1, off));
    m2 = fmaxf(m2, __shfl_down(m2, off));
    m3 = fmaxf(m3, __shfl_down(m3, off));
  }
  if (lane == 0) {
    redv[w * 3 + 0] = m1; redv[w * 3 + 1] = m2; redv[w * 3 + 2] = m3;
  }
  __syncthreads();                 // barrier 1: publishes redv + wraw1/2/3 + bias tables
  float s1 = 0.f, s2 = 0.f, s3 = 0.f;
  #pragma unroll
  for (int i = 0; i < 4; ++i) {
    s1 = fmaxf(s1, redv[i * 3 + 0]);
    s2 = fmaxf(s2, redv[i * 3 + 1]);
    s3 = fmaxf(s3, redv[i * 3 + 2]);
  }
  s1 /= QMAXF; s2 /= QMAXF; s3 /= QMAXF;
  const float rs1 = 1.0f / s1, rs2 = 1.0f / s2, rs3 = 1.0f / s3;

  // ---- weight fragments (integer-valued bf16) from LDS (reciprocal-mul quant) ----
  short8 w1f[4];
  #pragma unroll
  for (int t = 0; t < 4; ++t) {
    #pragma unroll
    for (int j = 0; j < 8; ++j) {
      int k = 8 * q + j;
      float wv = (k < 17) ? wraw1[(16 * t + bi) * 17 + k] : 0.f;
      float wi = fminf(fmaxf(rintf(wv * rs1), -QMAXF), QMAXF);
      w1f[t][j] = bf16i(wi);
    }
  }
  // K-permutation: eta = 32s + 16(j>>2) + 4q + (j&3) so layer-L C/D regs feed layer-(L+1) B-frags.
  short8 w2f[4][2];
  #pragma unroll
  for (int t = 0; t < 4; ++t) {
    #pragma unroll
    for (int s = 0; s < 2; ++s) {
      #pragma unroll
      for (int j = 0; j < 8; ++j) {
        int eta = 32 * s + 16 * (j >> 2) + 4 * q + (j & 3);
        float wv = wraw2[(16 * t + bi) * 65 + eta];
        float wi = fminf(fmaxf(rintf(wv * rs2), -QMAXF), QMAXF);
        w2f[t][s][j] = bf16i(wi);
      }
    }
  }
  short8 w3f[2];
  #pragma unroll
  for (int s = 0; s < 2; ++s) {
    #pragma unroll
    for (int j = 0; j < 8; ++j) {
      int eta = 32 * s + 16 * (j >> 2) + 4 * q + (j & 3);
      float wv = (bi < 6) ? wraw3[bi * 65 + eta] : 0.f;
      float wi = fminf(fmaxf(rintf(wv * rs3), -QMAXF), QMAXF);
      w3f[s][j] = bf16i(wi);
    }
  }

  __syncthreads();                 // barrier 2: weight LDS dead -> safe to reuse for x staging

  const float g1 = (s1 * step) * istep;
  const float g2 = (s2 * step) * istep;
  const float sc3 = s3 * step;

  // ---- scalarized work decomposition over 2-tile supertiles ----
  const int ntiles = B >> 4;                                   // 65536
  const int nSup   = ntiles >> 1;                              // 32768 supertiles (32 rows each)
  const int nw     = (int)(gridDim.x << 2);                    // 5120 waves
  const int wid    = __builtin_amdgcn_readfirstlane((int)(blockIdx.x << 2) + w);
  // per-wave supertile count (scalar): supertiles wid, wid+nw, ... < nSup
  const int myIter = (wid < nSup) ? ((nSup - 1 - wid) / nw + 1) : 0;   // 6 or 7

  float* xb = smem + w * 1152;                                 // two 576-dword buffers

  const int lane4 = lane * 4;                                  // dword offsets for staging
  const int fbase = bi * 17 + 8 * q;                           // frag base (q<2)
  const int fb2   = bi * 17 + 16;                              // q==2 single element
  const int tlane = 512 + imin(lane, 31);                      // clamped tail source offset

  // stage one supertile (544 dw contiguous + 32-dw pad = 576):
  // 2x dwordx4 (dw 0..511) + 1x dword (64 lanes write dw 512..575 EXACTLY; src clamped)
  auto stage = [&](int s, float* buf) {
    const float* tp = x + (size_t)s * 544;
    gld16(tp + lane4,        buf);                             // dw   0..255
    gld16(tp + 256 + lane4,  buf + 256);                       // dw 256..511
    gld4 (tp + tlane,        buf + 512);                       // dw 512..575 (543 real max)
  };

  const floatx4 zero4 = {0.f, 0.f, 0.f, 0.f};

  // ---- prologue: fill buffer 0 ----
  if (myIter > 0) stage(wid, xb);

  #pragma unroll 1
  for (int it = 0; it < myIter; ++it) {
    const int gs = wid + it * nw;                              // always < nSup (guarded)
    float* cur = xb + (it & 1) * 576;

    // retire this buffer's 3 loads; allow last iter's 1 store to stay outstanding
    if (it == 0) { asm volatile("s_waitcnt vmcnt(0)" ::: "memory"); }
    else         { asm volatile("s_waitcnt vmcnt(1)" ::: "memory"); }

    // issue next supertile into the other buffer (its old contents fully consumed)
    if (it + 1 < myIter) stage(wid + (it + 1) * nw, xb + ((it + 1) & 1) * 576);

    #pragma unroll 1
    for (int k = 0; k < 2; ++k) {
      float* tb = cur + k * 272;

      // fragment gather from LDS (stride-17-dword: max 2-way bank alias = free)
      float xr[8];
      if (q < 2) {
        #pragma unroll
        for (int j = 0; j < 8; ++j) xr[j] = tb[fbase + j];
      } else if (q == 2) {
        xr[0] = tb[fb2];
        #pragma unroll
        for (int j = 1; j < 8; ++j) xr[j] = 0.f;
      } else {
        #pragma unroll
        for (int j = 0; j < 8; ++j) xr[j] = 0.f;
      }

      // input quant -> B-frag: lane holds Xq[row=bi][k=8q+j]
      uint4v ap;
      #pragma unroll
      for (int jp = 0; jp < 4; ++jp)
        ap[jp] = pack2(qclamp(xr[2 * jp] * istep), qclamp(xr[2 * jp + 1] * istep));
      short8 af = __builtin_bit_cast(short8, ap);

      // L1
      floatx4 c1[4];
      #pragma unroll
      for (int t = 0; t < 4; ++t)
        c1[t] = __builtin_amdgcn_mfma_f32_16x16x32_bf16(w1f[t], af, zero4, 0, 0, 0);

      uint4v h1u[2];
      #pragma unroll
      for (int t = 0; t < 4; ++t) {
        float4 bb = *(const float4*)(b1t + 16 * t + 4 * q);    // broadcast ds_read_b128
        float z0 = qclamp(fmaf(c1[t][0], g1, bb.x));
        float z1 = qclamp(fmaf(c1[t][1], g1, bb.y));
        float z2 = qclamp(fmaf(c1[t][2], g1, bb.z));
        float z3 = qclamp(fmaf(c1[t][3], g1, bb.w));
        h1u[t >> 1][(t & 1) * 2 + 0] = pack2(z0, z1);
        h1u[t >> 1][(t & 1) * 2 + 1] = pack2(z2, z3);
      }
      short8 h1a = __builtin_bit_cast(short8, h1u[0]);
      short8 h1b = __builtin_bit_cast(short8, h1u[1]);

      // L2 (K=64)
      floatx4 c2[4];
      #pragma unroll
      for (int t = 0; t < 4; ++t) {
        c2[t] = __builtin_amdgcn_mfma_f32_16x16x32_bf16(w2f[t][0], h1a, zero4, 0, 0, 0);
        c2[t] = __builtin_amdgcn_mfma_f32_16x16x32_bf16(w2f[t][1], h1b, c2[t], 0, 0, 0);
      }

      uint4v h2u[2];
      #pragma unroll
      for (int t = 0; t < 4; ++t) {
        float4 bb = *(const float4*)(b2t + 16 * t + 4 * q);
        float z0 = qclamp(fmaf(c2[t][0], g2, bb.x));
        float z1 = qclamp(fmaf(c2[t][1], g2, bb.y));
        float z2 = qclamp(fmaf(c2[t][2], g2, bb.z));
        float z3 = qclamp(fmaf(c2[t][3], g2, bb.w));
        h2u[t >> 1][(t & 1) * 2 + 0] = pack2(z0, z1);
        h2u[t >> 1][(t & 1) * 2 + 1] = pack2(z2, z3);
      }
      short8 h2a = __builtin_bit_cast(short8, h2u[0]);
      short8 h2b = __builtin_bit_cast(short8, h2u[1]);

      // L3
      floatx4 c3;
      c3 = __builtin_amdgcn_mfma_f32_16x16x32_bf16(w3f[0], h2a, zero4, 0, 0, 0);
      c3 = __builtin_amdgcn_mfma_f32_16x16x32_bf16(w3f[1], h2b, c3, 0, 0, 0);

      float4 b3v = *(const float4*)(b3t + 4 * q);
      float o0 = fmaf(c3[0], sc3, b3v.x);
      float o1 = fmaf(c3[1], sc3, b3v.y);
      float o2 = fmaf(c3[2], sc3, b3v.z);
      float o3 = fmaf(c3[3], sc3, b3v.w);

      // stage tile-k output IN-PLACE at cur[k*96] (always over input already consumed
      // in program order: k=0 over own gathered tile, k=1 over tile0's region).
      float* ob = cur + k * 96;
      if (q == 0) {
        *(float2*)(ob + bi * 6)     = make_float2(o0, o1);     // ds_write_b64, 24B stride
        *(float2*)(ob + bi * 6 + 2) = make_float2(o2, o3);
      } else if (q == 1) {
        *(float2*)(ob + bi * 6 + 4) = make_float2(o0, o1);
      }
    }

    asm volatile("" ::: "memory");                             // pin LDS write->read order
    // batched store of 32 rows x 6 = 192 dw = 768B contiguous: lanes 0..47 dwordx4
    if (lane < 48) {
      float4 v0 = *(const float4*)(cur + lane4);               // ds_read_b128, linear
      *(float4*)(out + (size_t)gs * 192 + lane4) = v0;
    }
  }
}

extern "C" void kernel_launch(void* const* d_in, const int* in_sizes, int n_in,
                              void* d_out, int out_size, void* d_ws, size_t ws_size,
                              hipStream_t stream) {
  const float* x  = (const float*)d_in[0];
  const float* W1 = (const float*)d_in[1];
  const float* b1 = (const float*)d_in[2];
  const float* W2 = (const float*)d_in[3];
  const float* b2 = (const float*)d_in[4];
  const float* W3 = (const float*)d_in[5];
  const float* b3 = (const float*)d_in[6];
  float* out = (float*)d_out;
  const int B = in_sizes[0] / 17;          // 1048576

  dim3 grid(1280), block(256);             // 5120 waves, 6-7 supertiles each; ~5 blocks/CU
  qmlp_fused<<<grid, block, 0, stream>>>(x, W1, b1, W2, b2, W3, b3, out, B);
}

// Round 8
// 185.412 us; speedup vs baseline: 1.0473x; 1.0239x over previous
//
#include <hip/hip_runtime.h>

// QuantizedActorMLP: x(1M,17) -> quant -> L1(17->64)+quantact -> L2(64->64)+quantact -> L3(64->6)
// Integer-exact bf16 MFMA (ints |n|<=127 exact in bf16, sums < 2^24 exact in fp32 acc).
// R17: T14 register-staged deep prefetch. Evidence chain:
//  - R11/R13 invariant: ~7650 cy/tile, ~1.9 TB/s effective; LDS staging caps in-flight
//    bytes at ~70KB/CU (LDS capacity). qquant ~4TB/s, copy 6.3TB/s = deeper flight.
//  - R14 (occupancy via cap) died to spills; R15 (reg loads, scattered) died to scatter;
//    R16 (2-tile supertiles, 5 blk/CU) regressed 2.2x -> reverted.
//  => R17 = R13 verbatim (4-tile supertiles, grid 1024, funnel store) with staging
//     replaced by: global -> 17 VGPR/lane coalesced (4x dwordx4 + 1x dword), depth-2
//     batches (A/B named regs, rule-20 safe), ds_write -> single wave-private LDS buf,
//     stride-17 gather unchanged. Same-wave DS in-order; compiler-managed vmcnt.
//     Bias LDS tables from R16 (verified) keep base VGPR ~88 -> total ~122 < 128.
//  In-flight read bytes/CU: 16 waves x 2 x 4.35KB = 139KB (2x R13).
//  Falsifiers: VGPR>128 (occupancy cliff) or WRITE_SIZE>>24.5MB (spill) -> revert R13.

typedef __attribute__((ext_vector_type(8))) short short8;    // MFMA A/B frag (8 bf16)
typedef __attribute__((ext_vector_type(4))) float floatx4;   // MFMA C/D frag
typedef __attribute__((ext_vector_type(4))) unsigned int uint4v;
typedef unsigned int uint;

__device__ __forceinline__ uint f32bits(float v) { union { float f; uint u; } c; c.f = v; return c.u; }
__device__ __forceinline__ short bf16i(float v) { return (short)(f32bits(v) >> 16); }
// pack two integer-valued f32 -> two bf16 in one uint (low = z0): one v_perm_b32
__device__ __forceinline__ uint pack2(float z0, float z1) {
  return __builtin_amdgcn_perm(f32bits(z1), f32bits(z0), 0x07060302u);
}
// round-to-nearest-even integer clamped to [-127,127]: v_med3 + v_rndne
__device__ __forceinline__ float qclamp(float v) {
  return __builtin_rintf(__builtin_amdgcn_fmed3f(v, -127.f, 127.f));
}
__device__ __forceinline__ int imin(int a, int b) { return a < b ? a : b; }

__global__ void __launch_bounds__(256) qmlp_fused(
    const float* __restrict__ x,
    const float* __restrict__ W1, const float* __restrict__ b1,
    const float* __restrict__ W2, const float* __restrict__ b2,
    const float* __restrict__ W3, const float* __restrict__ b3,
    float* __restrict__ out, int B)
{
  constexpr float QMAXF = 127.0f;
  constexpr float SCALE = 1.33f;
  const float step  = SCALE / QMAXF;
  const float istep = QMAXF / SCALE;

  // One shared pool, two lifetimes:
  //  preamble: wraw1[0..1088) wraw2[1088..5248) wraw3[5248..5638) redv[5638..5650)
  //  main loop: per-wave single x buffer [w*1088, +1088)  (4352 dw, overlays wraw1/2)
  //  persistent: bias tables b1t[5650..5714) b2t[5714..5778) b3t[5778..5794)
  __shared__ __align__(16) float smem[5794];
  float* wraw1 = smem;            // W1 raw, pitch 17
  float* wraw2 = smem + 1088;     // W2 raw, pitch 65 (pad kills gather conflicts)
  float* wraw3 = smem + 5248;     // W3 raw, pitch 65
  float* redv  = smem + 5638;     // per-wave (m1,m2,m3)
  float* b1t   = smem + 5650;     // b1[n]*istep
  float* b2t   = smem + 5714;     // b2[n]*istep
  float* b3t   = smem + 5778;     // b3[n] (n<6) else 0

  const int tid  = threadIdx.x;
  const int lane = tid & 63;
  const int bi   = lane & 15;
  const int q    = lane >> 4;
  const int w    = tid >> 6;

  // ---- coalesced staging of raw weights into LDS, max-abs fused into the load ----
  float m1 = 0.f, m2 = 0.f, m3 = 0.f;
  for (int i = tid; i < 272; i += 256) {                       // W1: 1088 floats = 272 float4
    float4 v = ((const float4*)W1)[i];
    ((float4*)wraw1)[i] = v;
    m1 = fmaxf(m1, fmaxf(fmaxf(fabsf(v.x), fabsf(v.y)), fmaxf(fabsf(v.z), fabsf(v.w))));
  }
  for (int i = tid; i < 1024; i += 256) {                      // W2: 4096 floats = 1024 float4
    float4 v = ((const float4*)W2)[i];
    int r = i >> 4, c0 = (i & 15) * 4;                         // no float4 crosses a 64-row
    float* dst = &wraw2[r * 65 + c0];
    dst[0] = v.x; dst[1] = v.y; dst[2] = v.z; dst[3] = v.w;
    m2 = fmaxf(m2, fmaxf(fmaxf(fabsf(v.x), fabsf(v.y)), fmaxf(fabsf(v.z), fabsf(v.w))));
  }
  for (int i = tid; i < 96; i += 256) {                        // W3: 384 floats = 96 float4
    float4 v = ((const float4*)W3)[i];
    int r = i >> 4, c0 = (i & 15) * 4;
    float* dst = &wraw3[r * 65 + c0];
    dst[0] = v.x; dst[1] = v.y; dst[2] = v.z; dst[3] = v.w;
    m3 = fmaxf(m3, fmaxf(fmaxf(fabsf(v.x), fabsf(v.y)), fmaxf(fabsf(v.z), fabsf(v.w))));
  }
  // bias tables (persistent region, disjoint from wraw* and x-buffers): written once
  if (tid < 64) {
    b1t[tid] = b1[tid] * istep;
    b2t[tid] = b2[tid] * istep;
  }
  if (tid < 16) b3t[tid] = (tid < 6) ? b3[tid] : 0.f;

  #pragma unroll
  for (int off = 32; off > 0; off >>= 1) {
    m1 = fmaxf(m1, __shfl_down(m1, off));
    m2 = fmaxf(m2, __shfl_down(m2, off));
    m3 = fmaxf(m3, __shfl_down(m3, off));
  }
  if (lane == 0) {
    redv[w * 3 + 0] = m1; redv[w * 3 + 1] = m2; redv[w * 3 + 2] = m3;
  }
  __syncthreads();                 // barrier 1: publishes redv + wraw1/2/3 + bias tables
  float s1 = 0.f, s2 = 0.f, s3 = 0.f;
  #pragma unroll
  for (int i = 0; i < 4; ++i) {
    s1 = fmaxf(s1, redv[i * 3 + 0]);
    s2 = fmaxf(s2, redv[i * 3 + 1]);
    s3 = fmaxf(s3, redv[i * 3 + 2]);
  }
  s1 /= QMAXF; s2 /= QMAXF; s3 /= QMAXF;
  const float rs1 = 1.0f / s1, rs2 = 1.0f / s2, rs3 = 1.0f / s3;

  // ---- weight fragments (integer-valued bf16) from LDS (reciprocal-mul quant) ----
  short8 w1f[4];
  #pragma unroll
  for (int t = 0; t < 4; ++t) {
    #pragma unroll
    for (int j = 0; j < 8; ++j) {
      int k = 8 * q + j;
      float wv = (k < 17) ? wraw1[(16 * t + bi) * 17 + k] : 0.f;
      float wi = fminf(fmaxf(rintf(wv * rs1), -QMAXF), QMAXF);
      w1f[t][j] = bf16i(wi);
    }
  }
  // K-permutation: eta = 32s + 16(j>>2) + 4q + (j&3) so layer-L C/D regs feed layer-(L+1) B-frags.
  short8 w2f[4][2];
  #pragma unroll
  for (int t = 0; t < 4; ++t) {
    #pragma unroll
    for (int s = 0; s < 2; ++s) {
      #pragma unroll
      for (int j = 0; j < 8; ++j) {
        int eta = 32 * s + 16 * (j >> 2) + 4 * q + (j & 3);
        float wv = wraw2[(16 * t + bi) * 65 + eta];
        float wi = fminf(fmaxf(rintf(wv * rs2), -QMAXF), QMAXF);
        w2f[t][s][j] = bf16i(wi);
      }
    }
  }
  short8 w3f[2];
  #pragma unroll
  for (int s = 0; s < 2; ++s) {
    #pragma unroll
    for (int j = 0; j < 8; ++j) {
      int eta = 32 * s + 16 * (j >> 2) + 4 * q + (j & 3);
      float wv = (bi < 6) ? wraw3[bi * 65 + eta] : 0.f;
      float wi = fminf(fmaxf(rintf(wv * rs3), -QMAXF), QMAXF);
      w3f[s][j] = bf16i(wi);
    }
  }

  __syncthreads();                 // barrier 2: weight LDS dead -> safe to reuse for x buffer

  const float g1 = (s1 * step) * istep;
  const float g2 = (s2 * step) * istep;
  const float sc3 = s3 * step;

  // ---- scalarized work decomposition over 4-tile supertiles ----
  const int ntiles = B >> 4;                                   // 65536
  const int nSup   = ntiles >> 2;                              // 16384 supertiles (64 rows each)
  const int nw     = (int)(gridDim.x << 2);                    // 4096 waves
  const int wid    = __builtin_amdgcn_readfirstlane((int)(blockIdx.x << 2) + w);
  const int nIter  = (nSup + nw - 1) / nw;                     // 4
  const int lastS  = nSup - 1;

  float* xb = smem + w * 1088;                                 // ONE 1088-dword buffer/wave

  const int lane4 = lane * 4;                                  // dword offsets
  const int fbase = bi * 17 + 8 * q;                           // frag base (q<2)
  const int fb2   = bi * 17 + 16;                              // q==2 single element

  // ---- register batch: one supertile = 17 VGPRs/lane, fully coalesced loads ----
  struct Batch { float4 v[4]; float t; };
  auto loadB = [&](int s, Batch& b) {
    const float* tp = x + (size_t)s * 1088;
    #pragma unroll
    for (int c = 0; c < 4; ++c)
      b.v[c] = *(const float4*)(tp + 256 * c + lane4);         // 4x global_load_dwordx4
    b.t = tp[1024 + lane];                                     // 1x global_load_dword
  };
  auto writeB = [&](const Batch& b) {                          // redistribute via LDS
    #pragma unroll
    for (int c = 0; c < 4; ++c)
      *(float4*)(xb + 256 * c + lane4) = b.v[c];               // linear ds_write_b128
    xb[1024 + lane] = b.t;                                     // ds_write_b32, exact
  };

  const floatx4 zero4 = {0.f, 0.f, 0.f, 0.f};

  // ---- prologue: depth-2 register prefetch (named A/Bb: rule-20 static indexing) ----
  Batch A, Bb;
  loadB(imin(wid, lastS), A);
  loadB(imin(wid + nw, lastS), Bb);

  #pragma unroll 1
  for (int it = 0; it < nIter; ++it) {
    const int gs = imin(wid + it * nw, lastS);

    // commit the oldest batch to LDS (compiler emits precise vmcnt for just its 5 loads),
    // then immediately refill its registers with batch it+2 (WAR after ds_write).
    if ((it & 1) == 0) {
      writeB(A);
      if (it + 2 < nIter) loadB(imin(wid + (it + 2) * nw, lastS), A);
    } else {
      writeB(Bb);
      if (it + 2 < nIter) loadB(imin(wid + (it + 2) * nw, lastS), Bb);
    }
    asm volatile("" ::: "memory");                             // pin ds_write -> gather order

    #pragma unroll 1
    for (int k = 0; k < 4; ++k) {
      float* tb = xb + k * 272;

      // fragment gather from LDS (stride-17-dword: max 2-way bank alias = free)
      float xr[8];
      if (q < 2) {
        #pragma unroll
        for (int j = 0; j < 8; ++j) xr[j] = tb[fbase + j];
      } else if (q == 2) {
        xr[0] = tb[fb2];
        #pragma unroll
        for (int j = 1; j < 8; ++j) xr[j] = 0.f;
      } else {
        #pragma unroll
        for (int j = 0; j < 8; ++j) xr[j] = 0.f;
      }

      // input quant -> B-frag: lane holds Xq[row=bi][k=8q+j]
      uint4v ap;
      #pragma unroll
      for (int jp = 0; jp < 4; ++jp)
        ap[jp] = pack2(qclamp(xr[2 * jp] * istep), qclamp(xr[2 * jp + 1] * istep));
      short8 af = __builtin_bit_cast(short8, ap);

      // L1
      floatx4 c1[4];
      #pragma unroll
      for (int t = 0; t < 4; ++t)
        c1[t] = __builtin_amdgcn_mfma_f32_16x16x32_bf16(w1f[t], af, zero4, 0, 0, 0);

      uint4v h1u[2];
      #pragma unroll
      for (int t = 0; t < 4; ++t) {
        float4 bb = *(const float4*)(b1t + 16 * t + 4 * q);    // broadcast ds_read_b128
        float z0 = qclamp(fmaf(c1[t][0], g1, bb.x));
        float z1 = qclamp(fmaf(c1[t][1], g1, bb.y));
        float z2 = qclamp(fmaf(c1[t][2], g1, bb.z));
        float z3 = qclamp(fmaf(c1[t][3], g1, bb.w));
        h1u[t >> 1][(t & 1) * 2 + 0] = pack2(z0, z1);
        h1u[t >> 1][(t & 1) * 2 + 1] = pack2(z2, z3);
      }
      short8 h1a = __builtin_bit_cast(short8, h1u[0]);
      short8 h1b = __builtin_bit_cast(short8, h1u[1]);

      // L2 (K=64)
      floatx4 c2[4];
      #pragma unroll
      for (int t = 0; t < 4; ++t) {
        c2[t] = __builtin_amdgcn_mfma_f32_16x16x32_bf16(w2f[t][0], h1a, zero4, 0, 0, 0);
        c2[t] = __builtin_amdgcn_mfma_f32_16x16x32_bf16(w2f[t][1], h1b, c2[t], 0, 0, 0);
      }

      uint4v h2u[2];
      #pragma unroll
      for (int t = 0; t < 4; ++t) {
        float4 bb = *(const float4*)(b2t + 16 * t + 4 * q);
        float z0 = qclamp(fmaf(c2[t][0], g2, bb.x));
        float z1 = qclamp(fmaf(c2[t][1], g2, bb.y));
        float z2 = qclamp(fmaf(c2[t][2], g2, bb.z));
        float z3 = qclamp(fmaf(c2[t][3], g2, bb.w));
        h2u[t >> 1][(t & 1) * 2 + 0] = pack2(z0, z1);
        h2u[t >> 1][(t & 1) * 2 + 1] = pack2(z2, z3);
      }
      short8 h2a = __builtin_bit_cast(short8, h2u[0]);
      short8 h2b = __builtin_bit_cast(short8, h2u[1]);

      // L3
      floatx4 c3;
      c3 = __builtin_amdgcn_mfma_f32_16x16x32_bf16(w3f[0], h2a, zero4, 0, 0, 0);
      c3 = __builtin_amdgcn_mfma_f32_16x16x32_bf16(w3f[1], h2b, c3, 0, 0, 0);

      float4 b3v = *(const float4*)(b3t + 4 * q);
      float o0 = fmaf(c3[0], sc3, b3v.x);
      float o1 = fmaf(c3[1], sc3, b3v.y);
      float o2 = fmaf(c3[2], sc3, b3v.z);
      float o3 = fmaf(c3[3], sc3, b3v.w);

      // stage tile-k output IN-PLACE at xb[k*96]: every write lands on input already
      // consumed in program order (verified R13). ds_write_b64, 24B stride.
      float* ob = xb + k * 96;
      if (q == 0) {
        *(float2*)(ob + bi * 6)     = make_float2(o0, o1);
        *(float2*)(ob + bi * 6 + 2) = make_float2(o2, o3);
      } else if (q == 1) {
        *(float2*)(ob + bi * 6 + 4) = make_float2(o0, o1);
      }
    }

    asm volatile("" ::: "memory");                             // pin LDS write->read order
    // batched store of 64 rows x 6 = 384 dw = 1536B contiguous: 2 dwordx4 stores
    {
      float4 v0 = *(const float4*)(xb + lane4);                // dw 0..255
      *(float4*)(out + (size_t)gs * 384 + lane4) = v0;
      if (lane < 32) {
        float4 v1 = *(const float4*)(xb + 256 + lane4);        // dw 256..383
        *(float4*)(out + (size_t)gs * 384 + 256 + lane4) = v1;
      }
    }
    asm volatile("" ::: "memory");                             // next writeB only after reads
  }
}

extern "C" void kernel_launch(void* const* d_in, const int* in_sizes, int n_in,
                              void* d_out, int out_size, void* d_ws, size_t ws_size,
                              hipStream_t stream) {
  const float* x  = (const float*)d_in[0];
  const float* W1 = (const float*)d_in[1];
  const float* b1 = (const float*)d_in[2];
  const float* W2 = (const float*)d_in[3];
  const float* b2 = (const float*)d_in[4];
  const float* W3 = (const float*)d_in[5];
  const float* b3 = (const float*)d_in[6];
  float* out = (float*)d_out;
  const int B = in_sizes[0] / 17;          // 1048576

  dim3 grid(1024), block(256);             // 4096 waves x 4 super-iterations, 4 blocks/CU
  qmlp_fused<<<grid, block, 0, stream>>>(x, W1, b1, W2, b2, W3, b3, out, B);
}